// Round 2
// baseline (164.230 us; speedup 1.0000x reference)
//
#include <hip/hip_runtime.h>

#define NQ   6
#define DIM  64      // 2^NQ
#define NMOD 32
#define NCL  32
#define BATCH 2048
#define NCLS 150
#define KF   192     // NMOD*NQ
#define NROWS (BATCH*NMOD)   // 65536

// ws layout (float offsets):
//   UT    : NMOD*DIM*DIM*2 = 262144   (per-module unitary, ROW-major, float2)
//   camps : NROWS*NQ*2     = 786432   (cos/sin of 0.5*angle)
//   outs  : BATCH*KF       = 393216   (per-module Z expectations)
#define OFF_UT    0
#define OFF_CAMPS 262144
#define OFF_OUTS  1048576

// ---------------------------------------------------------------------------
// K0: angles = parts @ Wp^T + bp, then store (cos(a/2), sin(a/2)).
__global__ __launch_bounds__(192) void k_angles(const float* __restrict__ features,
                                                const float* __restrict__ Wp,
                                                const float* __restrict__ bp,
                                                float* __restrict__ camps) {
    __shared__ float ldsA[64 * 33];   // [d][r], padded stride 33
    __shared__ float ldsW[NQ * 64];
    int tid = threadIdx.x;
    int rowbase = blockIdx.x * 32;
    const float* src = features + (size_t)rowbase * 64;
    for (int idx = tid; idx < 32 * 64; idx += 192) {
        int r = idx >> 6, d = idx & 63;
        ldsA[d * 33 + r] = src[idx];
    }
    for (int idx = tid; idx < NQ * 64; idx += 192) ldsW[idx] = Wp[idx];
    __syncthreads();

    int q = tid >> 5;        // 0..5
    int r = tid & 31;        // 0..31
    float acc = 0.f;
#pragma unroll
    for (int d = 0; d < 64; ++d) acc += ldsA[d * 33 + r] * ldsW[q * 64 + d];
    float half = 0.5f * (acc + bp[q]);
    float s, c;
    sincosf(half, &s, &c);
    int row = rowbase + r;
    camps[(row * NQ + q) * 2 + 0] = c;
    camps[(row * NQ + q) * 2 + 1] = s;
}

// ---------------------------------------------------------------------------
// k_prep: fused cstab + unitary build. One wave per (p, col); lane = basis idx.
// RX(q) via shfl_xor; the 6-CNOT block is one fixed permutation -> ds_permute.
// Stores U ROW-major: UT2[p][i=lane][j=col].
__global__ __launch_bounds__(256) void k_prep(const float* __restrict__ qw,
                                              float* __restrict__ UTf) {
    __shared__ float2 csl[NCL * NQ];
    int tid = threadIdx.x;
    int lane = tid & 63;
    int w = tid >> 6;
    int p = blockIdx.x >> 4;
    int col = ((blockIdx.x & 15) << 2) + w;

    if (tid < NCL * NQ) {
        float s, c;
        sincosf(0.5f * qw[p * NCL * NQ + tid], &s, &c);
        csl[tid] = make_float2(c, s);
    }
    __syncthreads();

    // fixed CNOT-ring permutation: push destination for this lane
    int dst = lane;
#pragma unroll
    for (int q = 0; q < NQ; ++q) {
        int cm = 1 << (5 - q), tm = 1 << (5 - ((q + 1) % 6));
        dst ^= (dst & cm) ? tm : 0;
    }
    int dst_b = dst << 2;

    float re = (lane == col) ? 1.f : 0.f;
    float im = 0.f;

    for (int layer = 0; layer < NCL; ++layer) {
#pragma unroll
        for (int q = 0; q < NQ; ++q) {
            float2 cs = csl[layer * NQ + q];
            int mask = 1 << (5 - q);
            float pre = __shfl_xor(re, mask, 64);
            float pim = __shfl_xor(im, mask, 64);
            float nre = fmaf(cs.x, re, cs.y * pim);
            float nim = fmaf(cs.x, im, -cs.y * pre);
            re = nre;
            im = nim;
        }
        re = __int_as_float(__builtin_amdgcn_ds_permute(dst_b, __float_as_int(re)));
        im = __int_as_float(__builtin_amdgcn_ds_permute(dst_b, __float_as_int(im)));
    }
    float2* UT2 = (float2*)UTf;
    UT2[p * (DIM * DIM) + lane * DIM + col] = make_float2(re, im);
}

// ---------------------------------------------------------------------------
// k_circuit: lane = batch element. psi[64] in registers; U rows via
// wave-uniform loads; sign-reduction folded into register adds.
// Block = 4 waves, same (p, 64-batch tile); wave w does rows i in [16w,16w+16).
__global__ __launch_bounds__(256, 4) void k_circuit(const float* __restrict__ camps,
                                                    const float* __restrict__ UTf,
                                                    float* __restrict__ outs) {
    __shared__ float zl[4][5][64];
    int tid = threadIdx.x;
    int lane = tid & 63;
    int w = tid >> 6;
    int wq = __builtin_amdgcn_readfirstlane(w);
    int p = blockIdx.x & 31;
    int btile = blockIdx.x >> 5;
    int b = btile * 64 + lane;

    // load cos/sin pairs for this (b,p): 12 contiguous floats
    float ca[12];
    {
        const float4* cp = (const float4*)(camps + (size_t)(b * NMOD + p) * NQ * 2);
        float4 c0 = cp[0], c1 = cp[1], c2 = cp[2];
        ca[0] = c0.x; ca[1] = c0.y; ca[2] = c0.z; ca[3] = c0.w;
        ca[4] = c1.x; ca[5] = c1.y; ca[6] = c1.z; ca[7] = c1.w;
        ca[8] = c2.x; ca[9] = c2.y; ca[10] = c2.z; ca[11] = c2.w;
    }

    // build product state psi[64] by doubling: qubit q -> bit (5-q)
    float psi[DIM];
    psi[0] = 1.f;
#pragma unroll
    for (int q = 5; q >= 0; --q) {
        int sz = 1 << (5 - q);
        float c = ca[2 * q], s = ca[2 * q + 1];
#pragma unroll
        for (int k = 0; k < 64; ++k) {
            if (k < sz) {
                psi[k + sz] = psi[k] * s;
                psi[k] = psi[k] * c;
            }
        }
    }

    float ps = 0.f, z2 = 0.f, z3 = 0.f, z4 = 0.f, z5 = 0.f;
    const float4* Ubase = (const float4*)(UTf + (size_t)p * DIM * DIM * 2);

#pragma unroll
    for (int ii = 0; ii < 16; ++ii) {
        int i = wq * 16 + ii;
        const float4* Ur = Ubase + i * 32;   // 64 float2 = 32 float4
        float yre = 0.f, yim = 0.f;
#pragma unroll
        for (int j4 = 0; j4 < 32; ++j4) {
            float4 u = Ur[j4];
            yre = fmaf(u.x, psi[2 * j4], yre);
            yim = fmaf(u.y, psi[2 * j4], yim);
            yre = fmaf(u.z, psi[2 * j4 + 1], yre);
            yim = fmaf(u.w, psi[2 * j4 + 1], yim);
        }
        float prob = fmaf(yre, yre, yim * yim);
        ps += prob;
        z2 += (ii & 8) ? -prob : prob;   // q=2 <- bit3 of i
        z3 += (ii & 4) ? -prob : prob;   // q=3 <- bit2
        z4 += (ii & 2) ? -prob : prob;   // q=4 <- bit1
        z5 += (ii & 1) ? -prob : prob;   // q=5 <- bit0
    }

    zl[w][0][lane] = ps;
    zl[w][1][lane] = z2;
    zl[w][2][lane] = z3;
    zl[w][3][lane] = z4;
    zl[w][4][lane] = z5;
    __syncthreads();

    if (tid < 64) {
        float p0 = zl[0][0][tid], p1 = zl[1][0][tid], p2 = zl[2][0][tid], p3 = zl[3][0][tid];
        // q=0 sign <- bit5 of i = w>>1 ; q=1 sign <- bit4 of i = w&1
        float z0 = (p0 + p1) - (p2 + p3);
        float z1 = (p0 - p1) + (p2 - p3);
        float o2 = zl[0][1][tid] + zl[1][1][tid] + zl[2][1][tid] + zl[3][1][tid];
        float o3 = zl[0][2][tid] + zl[1][2][tid] + zl[2][2][tid] + zl[3][2][tid];
        float o4 = zl[0][3][tid] + zl[1][3][tid] + zl[2][3][tid] + zl[3][3][tid];
        float o5 = zl[0][4][tid] + zl[1][4][tid] + zl[2][4][tid] + zl[3][4][tid];
        int bb = btile * 64 + tid;
        float* o = outs + (size_t)bb * KF + p * NQ;
        o[0] = z0; o[1] = z1; o[2] = o2; o[3] = o3; o[4] = o4; o[5] = o5;
    }
}

// ---------------------------------------------------------------------------
// C: out = outs @ Wf^T + bf.
__global__ __launch_bounds__(256) void k_final(const float* __restrict__ outs,
                                               const float* __restrict__ Wf,
                                               const float* __restrict__ bf,
                                               float* __restrict__ out) {
    int tid = threadIdx.x;
    int b = blockIdx.x * 64 + (tid & 63);
    int c = blockIdx.y * 4 + (tid >> 6);
    if (c >= NCLS) return;
    float acc = bf[c];
    const float* orow = outs + (size_t)b * KF;
    const float* wrow = Wf + (size_t)c * KF;
#pragma unroll
    for (int k = 0; k < KF; k += 4) {
        float4 o = *(const float4*)&orow[k];
        float4 wv = *(const float4*)&wrow[k];
        acc = fmaf(o.x, wv.x, acc);
        acc = fmaf(o.y, wv.y, acc);
        acc = fmaf(o.z, wv.z, acc);
        acc = fmaf(o.w, wv.w, acc);
    }
    out[b * NCLS + c] = acc;
}

// ---------------------------------------------------------------------------
extern "C" void kernel_launch(void* const* d_in, const int* in_sizes, int n_in,
                              void* d_out, int out_size, void* d_ws, size_t ws_size,
                              hipStream_t stream) {
    const float* features = (const float*)d_in[0];
    const float* Wp       = (const float*)d_in[1];
    const float* bp       = (const float*)d_in[2];
    const float* qw       = (const float*)d_in[3];
    const float* Wf       = (const float*)d_in[4];
    const float* bf       = (const float*)d_in[5];
    float* out = (float*)d_out;
    float* ws  = (float*)d_ws;

    float* UT    = ws + OFF_UT;
    float* camps = ws + OFF_CAMPS;
    float* outsb = ws + OFF_OUTS;

    k_angles<<<NROWS / 32, 192, 0, stream>>>(features, Wp, bp, camps);
    k_prep<<<NMOD * 16, 256, 0, stream>>>(qw, UT);
    k_circuit<<<NMOD * (BATCH / 64), 256, 0, stream>>>(camps, UT, outsb);
    k_final<<<dim3(BATCH / 64, (NCLS + 3) / 4), 256, 0, stream>>>(outsb, Wf, bf, out);
}

// Round 4
// 164.153 us; speedup vs baseline: 1.0005x; 1.0005x over previous
//
#include <hip/hip_runtime.h>

#define NQ   6
#define DIM  64      // 2^NQ
#define NMOD 32
#define NCL  32
#define BATCH 2048
#define NCLS 150
#define KF   192     // NMOD*NQ
#define NROWS (BATCH*NMOD)   // 65536

// ws layout (float offsets):
//   UT    : NMOD*DIM*DIM*2 = 262144   (per-module unitary, ROW-major, float2)
//   outs  : BATCH*KF       = 393216   (per-module Z expectations)
#define OFF_UT    0
#define OFF_OUTS  262144

// ---------------------------------------------------------------------------
// k_prep: fused cstab + unitary build. One wave per (p, col); lane = basis idx.
// RX(q) via shfl_xor; the 6-CNOT block is one fixed permutation -> ds_permute.
// Stores U ROW-major: UT2[p][i=lane][j=col].
__global__ __launch_bounds__(256) void k_prep(const float* __restrict__ qw,
                                              float* __restrict__ UTf) {
    __shared__ float2 csl[NCL * NQ];
    int tid = threadIdx.x;
    int lane = tid & 63;
    int w = tid >> 6;
    int p = blockIdx.x >> 4;
    int col = ((blockIdx.x & 15) << 2) + w;

    if (tid < NCL * NQ) {
        float s, c;
        sincosf(0.5f * qw[p * NCL * NQ + tid], &s, &c);
        csl[tid] = make_float2(c, s);
    }
    __syncthreads();

    // fixed CNOT-ring permutation: push destination for this lane
    int dst = lane;
#pragma unroll
    for (int q = 0; q < NQ; ++q) {
        int cm = 1 << (5 - q), tm = 1 << (5 - ((q + 1) % 6));
        dst ^= (dst & cm) ? tm : 0;
    }
    int dst_b = dst << 2;

    float re = (lane == col) ? 1.f : 0.f;
    float im = 0.f;

    for (int layer = 0; layer < NCL; ++layer) {
#pragma unroll
        for (int q = 0; q < NQ; ++q) {
            float2 cs = csl[layer * NQ + q];
            int mask = 1 << (5 - q);
            float pre = __shfl_xor(re, mask, 64);
            float pim = __shfl_xor(im, mask, 64);
            float nre = fmaf(cs.x, re, cs.y * pim);
            float nim = fmaf(cs.x, im, -cs.y * pre);
            re = nre;
            im = nim;
        }
        re = __int_as_float(__builtin_amdgcn_ds_permute(dst_b, __float_as_int(re)));
        im = __int_as_float(__builtin_amdgcn_ds_permute(dst_b, __float_as_int(im)));
    }
    float2* UT2 = (float2*)UTf;
    UT2[p * (DIM * DIM) + lane * DIM + col] = make_float2(re, im);
}

// ---------------------------------------------------------------------------
// k_fused: angles GEMM + sincos + psi build + U matvec + measurement, one block
// per (p, 64-batch tile). 4 waves; lane = batch element within the tile.
__global__ __launch_bounds__(256, 4) void k_fused(const float* __restrict__ features,
                                                  const float* __restrict__ Wp,
                                                  const float* __restrict__ bp,
                                                  const float* __restrict__ UTf,
                                                  float* __restrict__ outs) {
    __shared__ float ldsA[64 * 65];     // [d][l], stride 65 (bank-free)
    __shared__ float ldsW[NQ * 64];
    __shared__ float camps_l[64 * 13];  // [l][12], stride 13 (bank-free)
    __shared__ float zl[4][5][64];

    int tid = threadIdx.x;
    int lane = tid & 63;
    int w = tid >> 6;
    int wq = __builtin_amdgcn_readfirstlane(w);
    int p = blockIdx.x & 31;
    int btile = blockIdx.x >> 5;

    // ---- stage 0: load feature tile (64 rows x 64 floats) + Wp into LDS ----
    {
        int l = tid >> 2;               // 0..63  (batch element)
        int quarter = tid & 3;          // 16-float chunk
        const float* src = features + (size_t)(btile * 64 + l) * 2048 + p * 64
                         + quarter * 16;
        float4 v0 = *(const float4*)(src + 0);
        float4 v1 = *(const float4*)(src + 4);
        float4 v2 = *(const float4*)(src + 8);
        float4 v3 = *(const float4*)(src + 12);
        int d0 = quarter * 16;
        float tmp[16] = {v0.x,v0.y,v0.z,v0.w, v1.x,v1.y,v1.z,v1.w,
                         v2.x,v2.y,v2.z,v2.w, v3.x,v3.y,v3.z,v3.w};
#pragma unroll
        for (int j = 0; j < 16; ++j) ldsA[(d0 + j) * 65 + l] = tmp[j];
        // NQ*64 = 384 > 256 threads: MUST be a strided loop (R3 bug was `if`)
        for (int idx = tid; idx < NQ * 64; idx += 256) ldsW[idx] = Wp[idx];
    }
    __syncthreads();

    // ---- stage 1: angles = A @ Wp^T + bp ; store cos/sin of half-angle ----
    {
        int l = tid & 63;
        int q0 = tid >> 6;              // 0..3
        float acc0 = 0.f, acc1 = 0.f;
        bool two = (q0 < 2);
        int q1 = q0 + 4;
#pragma unroll
        for (int d = 0; d < 64; ++d) {
            float a = ldsA[d * 65 + l];
            acc0 = fmaf(a, ldsW[q0 * 64 + d], acc0);
            if (two) acc1 = fmaf(a, ldsW[q1 * 64 + d], acc1);
        }
        float s, c;
        sincosf(0.5f * (acc0 + bp[q0]), &s, &c);
        camps_l[l * 13 + 2 * q0 + 0] = c;
        camps_l[l * 13 + 2 * q0 + 1] = s;
        if (two) {
            sincosf(0.5f * (acc1 + bp[q1]), &s, &c);
            camps_l[l * 13 + 2 * q1 + 0] = c;
            camps_l[l * 13 + 2 * q1 + 1] = s;
        }
    }
    __syncthreads();

    // ---- stage 2: psi build (lane = batch elem) ----
    float ca[12];
#pragma unroll
    for (int j = 0; j < 12; ++j) ca[j] = camps_l[lane * 13 + j];

    float psi[DIM];
    psi[0] = 1.f;
#pragma unroll
    for (int q = 5; q >= 0; --q) {
        int sz = 1 << (5 - q);
        float c = ca[2 * q], s = ca[2 * q + 1];
#pragma unroll
        for (int k = 0; k < 64; ++k) {
            if (k < sz) {
                psi[k + sz] = psi[k] * s;
                psi[k] = psi[k] * c;
            }
        }
    }

    // ---- stage 3: y = U psi (wave w does rows 16w..16w+15), measurement ----
    float ps = 0.f, z2 = 0.f, z3 = 0.f, z4 = 0.f, z5 = 0.f;
    const float4* Ubase = (const float4*)(UTf + (size_t)p * DIM * DIM * 2);

#pragma unroll
    for (int ii = 0; ii < 16; ++ii) {
        int i = wq * 16 + ii;
        const float4* Ur = Ubase + i * 32;   // 64 float2 = 32 float4
        float yre = 0.f, yim = 0.f;
#pragma unroll
        for (int j4 = 0; j4 < 32; ++j4) {
            float4 u = Ur[j4];
            yre = fmaf(u.x, psi[2 * j4], yre);
            yim = fmaf(u.y, psi[2 * j4], yim);
            yre = fmaf(u.z, psi[2 * j4 + 1], yre);
            yim = fmaf(u.w, psi[2 * j4 + 1], yim);
        }
        float prob = fmaf(yre, yre, yim * yim);
        ps += prob;
        z2 += (ii & 8) ? -prob : prob;   // q=2 <- bit3 of i
        z3 += (ii & 4) ? -prob : prob;   // q=3 <- bit2
        z4 += (ii & 2) ? -prob : prob;   // q=4 <- bit1
        z5 += (ii & 1) ? -prob : prob;   // q=5 <- bit0
    }

    zl[w][0][lane] = ps;
    zl[w][1][lane] = z2;
    zl[w][2][lane] = z3;
    zl[w][3][lane] = z4;
    zl[w][4][lane] = z5;
    __syncthreads();

    if (tid < 64) {
        float p0 = zl[0][0][tid], p1 = zl[1][0][tid], p2 = zl[2][0][tid], p3 = zl[3][0][tid];
        // q=0 sign <- bit5 of i = w>>1 ; q=1 sign <- bit4 of i = w&1
        float z0 = (p0 + p1) - (p2 + p3);
        float z1 = (p0 - p1) + (p2 - p3);
        float o2 = zl[0][1][tid] + zl[1][1][tid] + zl[2][1][tid] + zl[3][1][tid];
        float o3 = zl[0][2][tid] + zl[1][2][tid] + zl[2][2][tid] + zl[3][2][tid];
        float o4 = zl[0][3][tid] + zl[1][3][tid] + zl[2][3][tid] + zl[3][3][tid];
        float o5 = zl[0][4][tid] + zl[1][4][tid] + zl[2][4][tid] + zl[3][4][tid];
        int bb = btile * 64 + tid;
        float* o = outs + (size_t)bb * KF + p * NQ;
        o[0] = z0; o[1] = z1; o[2] = o2; o[3] = o3; o[4] = o4; o[5] = o5;
    }
}

// ---------------------------------------------------------------------------
// k_final: out = outs @ Wf^T + bf.
__global__ __launch_bounds__(256) void k_final(const float* __restrict__ outs,
                                               const float* __restrict__ Wf,
                                               const float* __restrict__ bf,
                                               float* __restrict__ out) {
    int tid = threadIdx.x;
    int b = blockIdx.x * 64 + (tid & 63);
    int c = blockIdx.y * 4 + (tid >> 6);
    if (c >= NCLS) return;
    float acc = bf[c];
    const float* orow = outs + (size_t)b * KF;
    const float* wrow = Wf + (size_t)c * KF;
#pragma unroll
    for (int k = 0; k < KF; k += 4) {
        float4 o = *(const float4*)&orow[k];
        float4 wv = *(const float4*)&wrow[k];
        acc = fmaf(o.x, wv.x, acc);
        acc = fmaf(o.y, wv.y, acc);
        acc = fmaf(o.z, wv.z, acc);
        acc = fmaf(o.w, wv.w, acc);
    }
    out[b * NCLS + c] = acc;
}

// ---------------------------------------------------------------------------
extern "C" void kernel_launch(void* const* d_in, const int* in_sizes, int n_in,
                              void* d_out, int out_size, void* d_ws, size_t ws_size,
                              hipStream_t stream) {
    const float* features = (const float*)d_in[0];
    const float* Wp       = (const float*)d_in[1];
    const float* bp       = (const float*)d_in[2];
    const float* qw       = (const float*)d_in[3];
    const float* Wf       = (const float*)d_in[4];
    const float* bf       = (const float*)d_in[5];
    float* out = (float*)d_out;
    float* ws  = (float*)d_ws;

    float* UT    = ws + OFF_UT;
    float* outsb = ws + OFF_OUTS;

    k_prep<<<NMOD * 16, 256, 0, stream>>>(qw, UT);
    k_fused<<<NMOD * (BATCH / 64), 256, 0, stream>>>(features, Wp, bp, UT, outsb);
    k_final<<<dim3(BATCH / 64, (NCLS + 3) / 4), 256, 0, stream>>>(outsb, Wf, bf, out);
}

// Round 5
// 133.091 us; speedup vs baseline: 1.2340x; 1.2334x over previous
//
#include <hip/hip_runtime.h>

#define NQ   6
#define DIM  64      // 2^NQ
#define NMOD 32
#define NCL  32
#define BATCH 2048
#define NCLS 150
#define KF   192     // NMOD*NQ

// ws layout:
//   UB   : NMOD * 4 planes * 4096 ushorts = 1 MiB  (frag-ready bf16 U planes)
//          plane order: 0=re_hi 1=re_lo 2=im_hi 3=im_lo
//   outs : BATCH*KF floats at float-offset 262144
#define OFF_OUTS  262144

typedef short bf16x8 __attribute__((ext_vector_type(8)));
typedef float f32x16 __attribute__((ext_vector_type(16)));

// ---------------------------------------------------------------------------
// k_prep: build U_p (one wave per (p,col); lane = row i), then scatter-store
// split-bf16 planes in A-fragment-ready order:
//   frag id = (mi=i>>5)*4 + (kstep=j>>4); lane_a = (i&31) | ((j>>3)&1)<<5;
//   e = j&7  ->  ushort index F = fragid*512 + lane_a*8 + e
__global__ __launch_bounds__(256) void k_prep(const float* __restrict__ qw,
                                              unsigned short* __restrict__ UB) {
    __shared__ float2 csl[NCL * NQ];
    int tid = threadIdx.x;
    int lane = tid & 63;
    int w = tid >> 6;
    int p = blockIdx.x >> 4;
    int col = ((blockIdx.x & 15) << 2) + w;

    if (tid < NCL * NQ) {
        float s, c;
        sincosf(0.5f * qw[p * NCL * NQ + tid], &s, &c);
        csl[tid] = make_float2(c, s);
    }
    __syncthreads();

    // fixed CNOT-ring permutation (verified R4)
    int dst = lane;
#pragma unroll
    for (int q = 0; q < NQ; ++q) {
        int cm = 1 << (5 - q), tm = 1 << (5 - ((q + 1) % 6));
        dst ^= (dst & cm) ? tm : 0;
    }
    int dst_b = dst << 2;

    float re = (lane == col) ? 1.f : 0.f;
    float im = 0.f;
    for (int layer = 0; layer < NCL; ++layer) {
#pragma unroll
        for (int q = 0; q < NQ; ++q) {
            float2 cs = csl[layer * NQ + q];
            int mask = 1 << (5 - q);
            float pre = __shfl_xor(re, mask, 64);
            float pim = __shfl_xor(im, mask, 64);
            float nre = fmaf(cs.x, re, cs.y * pim);
            float nim = fmaf(cs.x, im, -cs.y * pre);
            re = nre;
            im = nim;
        }
        re = __int_as_float(__builtin_amdgcn_ds_permute(dst_b, __float_as_int(re)));
        im = __int_as_float(__builtin_amdgcn_ds_permute(dst_b, __float_as_int(im)));
    }

    // split-bf16 (truncation split: lo = x - trunc_bf16(x), exact)
    int F = (((lane >> 5) * 4 + (col >> 4)) << 9)
          + (((lane & 31) | (((col >> 3) & 1) << 5)) << 3) + (col & 7);
    unsigned short* base = UB + (size_t)p * 4 * 4096;
    unsigned int rb = __float_as_uint(re);
    float rhf = __uint_as_float(rb & 0xFFFF0000u);
    unsigned int rlb = __float_as_uint(re - rhf);
    unsigned int ib = __float_as_uint(im);
    float ihf = __uint_as_float(ib & 0xFFFF0000u);
    unsigned int ilb = __float_as_uint(im - ihf);
    base[0 * 4096 + F] = (unsigned short)(rb >> 16);
    base[1 * 4096 + F] = (unsigned short)(rlb >> 16);
    base[2 * 4096 + F] = (unsigned short)(ib >> 16);
    base[3 * 4096 + F] = (unsigned short)(ilb >> 16);
}

// ---------------------------------------------------------------------------
// k_fused: angles GEMM + sincos + psi + split-bf16 MFMA matvec + measurement.
// One block per (p, 64-batch tile); wave w: mi = w>>1 (rows), nb = w&1 (cols).
union SharedU {
    struct { float A[64 * 65]; float W[NQ * 64]; } s01;
    struct { unsigned short hi[64 * 72]; unsigned short lo[64 * 72]; } s23;  // row stride 72 ushorts = 144 B (16B-aligned)
};

__global__ __launch_bounds__(256, 4) void k_fused(const float* __restrict__ features,
                                                  const float* __restrict__ Wp,
                                                  const float* __restrict__ bp,
                                                  const unsigned short* __restrict__ UB,
                                                  float* __restrict__ outs) {
    __shared__ __align__(16) SharedU sh;
    __shared__ float camps_l[64 * 13];
    __shared__ float zacc[4][6][32];

    int tid = threadIdx.x;
    int lane = tid & 63;
    int w = tid >> 6;
    int p = blockIdx.x & 31;
    int btile = blockIdx.x >> 5;

    // ---- stage 0: feature tile + Wp into LDS (verbatim from passing R4) ----
    {
        int l = tid >> 2;
        int quarter = tid & 3;
        const float* src = features + (size_t)(btile * 64 + l) * 2048 + p * 64
                         + quarter * 16;
        float4 v0 = *(const float4*)(src + 0);
        float4 v1 = *(const float4*)(src + 4);
        float4 v2 = *(const float4*)(src + 8);
        float4 v3 = *(const float4*)(src + 12);
        int d0 = quarter * 16;
        float tmp[16] = {v0.x,v0.y,v0.z,v0.w, v1.x,v1.y,v1.z,v1.w,
                         v2.x,v2.y,v2.z,v2.w, v3.x,v3.y,v3.z,v3.w};
#pragma unroll
        for (int j = 0; j < 16; ++j) sh.s01.A[(d0 + j) * 65 + l] = tmp[j];
        for (int idx = tid; idx < NQ * 64; idx += 256) sh.s01.W[idx] = Wp[idx];
    }
    __syncthreads();

    // ---- stage 1: angles + sincos -> camps_l ----
    {
        int l = tid & 63;
        int q0 = tid >> 6;
        float acc0 = 0.f, acc1 = 0.f;
        bool two = (q0 < 2);
        int q1 = q0 + 4;
#pragma unroll
        for (int d = 0; d < 64; ++d) {
            float a = sh.s01.A[d * 65 + l];
            acc0 = fmaf(a, sh.s01.W[q0 * 64 + d], acc0);
            if (two) acc1 = fmaf(a, sh.s01.W[q1 * 64 + d], acc1);
        }
        float s, c;
        sincosf(0.5f * (acc0 + bp[q0]), &s, &c);
        camps_l[l * 13 + 2 * q0 + 0] = c;
        camps_l[l * 13 + 2 * q0 + 1] = s;
        if (two) {
            sincosf(0.5f * (acc1 + bp[q1]), &s, &c);
            camps_l[l * 13 + 2 * q1 + 0] = c;
            camps_l[l * 13 + 2 * q1 + 1] = s;
        }
    }
    __syncthreads();   // also fences ldsA reads before psiT overlay writes

    // ---- stage 2: psi -> split-bf16 planes in LDS, B-fragment-friendly ----
    // base[v] over qubits 0..4 (v-bit (4-q) <-> qubit q); j = 2v + b0, b0<->qubit5
    {
        float ca[12];
#pragma unroll
        for (int j = 0; j < 12; ++j) ca[j] = camps_l[lane * 13 + j];
        float base_[32];
        base_[0] = 1.f;
#pragma unroll
        for (int q = 4; q >= 0; --q) {
            int sz = 1 << (4 - q);
            float c = ca[2 * q], s = ca[2 * q + 1];
#pragma unroll
            for (int k = 0; k < 32; ++k) {
                if (k < sz) {
                    base_[k + sz] = base_[k] * s;
                    base_[k] = base_[k] * c;
                }
            }
        }
        float c5 = ca[10], s5 = ca[11];
        unsigned int* pHi = (unsigned int*)sh.s23.hi;
        unsigned int* pLo = (unsigned int*)sh.s23.lo;
#pragma unroll
        for (int v = w * 8; v < w * 8 + 8; ++v) {   // waves split the 32 dwords
            float f0 = base_[v] * c5, f1 = base_[v] * s5;   // j=2v, 2v+1
            unsigned int b0 = __float_as_uint(f0), b1 = __float_as_uint(f1);
            unsigned int hi = (b0 >> 16) | (b1 & 0xFFFF0000u);
            float f0h = __uint_as_float(b0 & 0xFFFF0000u);
            float f1h = __uint_as_float(b1 & 0xFFFF0000u);
            unsigned int l0 = __float_as_uint(f0 - f0h);
            unsigned int l1 = __float_as_uint(f1 - f1h);
            unsigned int lo = (l0 >> 16) | (l1 & 0xFFFF0000u);
            pHi[lane * 36 + v] = hi;
            pLo[lane * 36 + v] = lo;
        }
    }
    __syncthreads();

    // ---- stage 3: split-bf16 MFMA: C[i][b] = U[i][j] psi[j][b] ----
    int mi = w >> 1, nb = w & 1;
    int h = lane >> 5;
    int bloc = nb * 32 + (lane & 31);
    f32x16 accR, accI;
#pragma unroll
    for (int r = 0; r < 16; ++r) { accR[r] = 0.f; accI[r] = 0.f; }

    const unsigned short* Af = UB + (size_t)p * 16384 + ((mi * 4) << 9) + (lane << 3);
#pragma unroll
    for (int t = 0; t < 4; ++t) {
        const unsigned short* fp = Af + (t << 9);
        bf16x8 aRH = *(const bf16x8*)(fp + 0 * 4096);
        bf16x8 aRL = *(const bf16x8*)(fp + 1 * 4096);
        bf16x8 aIH = *(const bf16x8*)(fp + 2 * 4096);
        bf16x8 aIL = *(const bf16x8*)(fp + 3 * 4096);
        const unsigned short* bh = sh.s23.hi + bloc * 72 + t * 16 + 8 * h;
        const unsigned short* bl = sh.s23.lo + bloc * 72 + t * 16 + 8 * h;
        bf16x8 bH = *(const bf16x8*)bh;
        bf16x8 bL = *(const bf16x8*)bl;
        accR = __builtin_amdgcn_mfma_f32_32x32x16_bf16(aRH, bH, accR, 0, 0, 0);
        accR = __builtin_amdgcn_mfma_f32_32x32x16_bf16(aRH, bL, accR, 0, 0, 0);
        accR = __builtin_amdgcn_mfma_f32_32x32x16_bf16(aRL, bH, accR, 0, 0, 0);
        accI = __builtin_amdgcn_mfma_f32_32x32x16_bf16(aIH, bH, accI, 0, 0, 0);
        accI = __builtin_amdgcn_mfma_f32_32x32x16_bf16(aIH, bL, accI, 0, 0, 0);
        accI = __builtin_amdgcn_mfma_f32_32x32x16_bf16(aIL, bH, accI, 0, 0, 0);
    }

    // ---- measurement: row m = (reg&3) + 8*(reg>>2) + 4*h, i = mi*32 + m ----
    // qubit<->i-bit: q5<-bit0(reg&1) q4<-bit1(reg&2) q3<-bit2(h) q2<-bit3(g&1)
    //               q1<-bit4(g&2) q0<-bit5(mi)
    {
        float pr[16];
#pragma unroll
        for (int r = 0; r < 16; ++r)
            pr[r] = fmaf(accR[r], accR[r], accI[r] * accI[r]);

        float zA = 0.f, z1 = 0.f, z2 = 0.f, z4 = 0.f, z5 = 0.f;
#pragma unroll
        for (int g = 0; g < 4; ++g) {
            float r0 = pr[4 * g], r1 = pr[4 * g + 1], r2 = pr[4 * g + 2], r3 = pr[4 * g + 3];
            float a  = (r0 + r1) + (r2 + r3);
            float s5 = (r0 - r1) + (r2 - r3);
            float s4 = (r0 + r1) - (r2 + r3);
            zA += a;
            z2 += (g & 1) ? -a : a;
            z1 += (g & 2) ? -a : a;
            z5 += s5;
            z4 += s4;
        }
        // cross-half: qubit3 sign = (-1)^h
        float tA = __shfl_xor(zA, 32, 64);
        float z3 = h ? (tA - zA) : (zA - tA);
        zA += tA;
        z1 += __shfl_xor(z1, 32, 64);
        z2 += __shfl_xor(z2, 32, 64);
        z4 += __shfl_xor(z4, 32, 64);
        z5 += __shfl_xor(z5, 32, 64);

        if (lane < 32) {
            zacc[w][0][lane] = zA;   // qubit0 partial (mi sign applied below)
            zacc[w][1][lane] = z1;
            zacc[w][2][lane] = z2;
            zacc[w][3][lane] = z3;
            zacc[w][4][lane] = z4;
            zacc[w][5][lane] = z5;
        }
    }
    __syncthreads();

    if (tid < 64) {
        int nb2 = tid >> 5, c = tid & 31;
        int wA = nb2, wB = 2 + nb2;          // w = (mi<<1)|nb
        float z0 = zacc[wA][0][c] - zacc[wB][0][c];
        float o1 = zacc[wA][1][c] + zacc[wB][1][c];
        float o2 = zacc[wA][2][c] + zacc[wB][2][c];
        float o3 = zacc[wA][3][c] + zacc[wB][3][c];
        float o4 = zacc[wA][4][c] + zacc[wB][4][c];
        float o5 = zacc[wA][5][c] + zacc[wB][5][c];
        float* o = outs + (size_t)(btile * 64 + tid) * KF + p * NQ;
        o[0] = z0; o[1] = o1; o[2] = o2; o[3] = o3; o[4] = o4; o[5] = o5;
    }
}

// ---------------------------------------------------------------------------
// k_final: out = outs @ Wf^T + bf.
__global__ __launch_bounds__(256) void k_final(const float* __restrict__ outs,
                                               const float* __restrict__ Wf,
                                               const float* __restrict__ bf,
                                               float* __restrict__ out) {
    int tid = threadIdx.x;
    int b = blockIdx.x * 64 + (tid & 63);
    int c = blockIdx.y * 4 + (tid >> 6);
    if (c >= NCLS) return;
    float acc = bf[c];
    const float* orow = outs + (size_t)b * KF;
    const float* wrow = Wf + (size_t)c * KF;
#pragma unroll
    for (int k = 0; k < KF; k += 4) {
        float4 o = *(const float4*)&orow[k];
        float4 wv = *(const float4*)&wrow[k];
        acc = fmaf(o.x, wv.x, acc);
        acc = fmaf(o.y, wv.y, acc);
        acc = fmaf(o.z, wv.z, acc);
        acc = fmaf(o.w, wv.w, acc);
    }
    out[b * NCLS + c] = acc;
}

// ---------------------------------------------------------------------------
extern "C" void kernel_launch(void* const* d_in, const int* in_sizes, int n_in,
                              void* d_out, int out_size, void* d_ws, size_t ws_size,
                              hipStream_t stream) {
    const float* features = (const float*)d_in[0];
    const float* Wp       = (const float*)d_in[1];
    const float* bp       = (const float*)d_in[2];
    const float* qw       = (const float*)d_in[3];
    const float* Wf       = (const float*)d_in[4];
    const float* bf       = (const float*)d_in[5];
    float* out = (float*)d_out;
    float* ws  = (float*)d_ws;

    unsigned short* UB = (unsigned short*)ws;          // 1 MiB
    float* outsb = ws + OFF_OUTS;

    k_prep<<<NMOD * 16, 256, 0, stream>>>(qw, UB);
    k_fused<<<NMOD * (BATCH / 64), 256, 0, stream>>>(features, Wp, bp, UB, outsb);
    k_final<<<dim3(BATCH / 64, (NCLS + 3) / 4), 256, 0, stream>>>(outsb, Wf, bf, out);
}